// Round 18
// baseline (1405.656 us; speedup 1.0000x reference)
//
#include <hip/hip_runtime.h>

#define BN_ROWS 65536
#define DIMX 256
#define CDIM 1024
#define KCODES 4096
#define NSP 16            // code strips of 256
#define NSLOT 5           // candidate slots per strip (excl. min)
#define NENT 6            // entries per (row,strip) = 1 min + NSLOT
#define CMARG 12.0f       // strip capture margin (~10 sigma of int8 score err)
#define RMARG 12.0f       // refine filter margin above global coarse min
#define QS 24.0f          // int8 quantization scale
#define INV_S2 (1.0f / (QS * QS))
#define FLT_BIG 3.402823466e+38f

// ---------------- ws layout (bytes) ----------------
static const size_t OFF_ESQ   = 0;         // 4096 f32 (16KB)
static const size_t OFF_IDXF  = 16384;     // 65536 i32
static const size_t OFF_CROW  = 278528;    // 65536 f32
static const size_t OFF_EPOST = 540672;    // 4096*256 f32 (4MB)
static const size_t OFF_EI8   = 4734976;   // 4096*1024 i8 (4MB)
static const size_t OFF_NFLAG = 8929280;   // 1 i32 (+pad)
static const size_t OFF_FLAG  = 8929344;   // 65536 i32
static const size_t OFF_CAND  = 9191488;   // chunk * 96 entries * 8B
// zi8 = OFF_CAND + chunk*768 ; zf = zi8 + chunk*1024 (fp32 z, 4KB/row)
// per-row total: 768 + 1024 + 4096 = 5888 B

typedef __attribute__((ext_vector_type(4))) int i32x4;

#define GLOAD_LDS16(gsrc, ldst)                                                \
  __builtin_amdgcn_global_load_lds(                                            \
      (const __attribute__((address_space(1))) void*)(gsrc),                   \
      (__attribute__((address_space(3))) void*)(ldst), 16, 0, 0)

__device__ inline char q8(float f) {
  return (char)__float2int_rn(fminf(fmaxf(f * QS, -127.f), 127.f));
}
__device__ inline unsigned fkey(float s) {
  unsigned b = __float_as_uint(s);
  return b ^ ((unsigned)((int)b >> 31) | 0x80000000u);
}
__device__ inline float keyinv(unsigned k) {
  unsigned b = (k & 0x80000000u) ? (k ^ 0x80000000u) : ~k;
  return __uint_as_float(b);
}

// ---------------- K0: fused e_sq + E->int8 (single pass over embed) --------
__global__ __launch_bounds__(256) void k_prep_e(const float* __restrict__ embed,
                                                float* __restrict__ e_sq,
                                                char* __restrict__ Ei8) {
  const int t = threadIdx.x, wv = t >> 6, lane = t & 63;
  const size_t row = blockIdx.x;
  float4 v = *(const float4*)(embed + row * CDIM + t * 4);
  *(char4*)(Ei8 + row * CDIM + t * 4) =
      make_char4(q8(v.x), q8(v.y), q8(v.z), q8(v.w));
  float s = v.x * v.x + v.y * v.y + v.z * v.z + v.w * v.w;
#pragma unroll
  for (int o = 32; o > 0; o >>= 1) s += __shfl_xor(s, o);
  __shared__ float wsum[4];
  if (lane == 0) wsum[wv] = s;
  __syncthreads();
  if (t == 0) e_sq[row] = wsum[0] + wsum[1] + wsum[2] + wsum[3];
}

// ---------------- K1: LN + GELU + @w_pre -> z fp32 + z int8 -----------------
// block = 512 threads, 32 rows/block, 2 output cols/thread (acc[32][2])
// halves per-row w_pre L2/L3 traffic vs 16-row/256-thr; z bit-identical
__global__ __launch_bounds__(512) void k_ln_gelu_gemm(
    const float* __restrict__ x, const float* __restrict__ ln_g,
    const float* __restrict__ ln_b, const float* __restrict__ w_pre,
    const float* __restrict__ b_pre, float* __restrict__ zf,
    char* __restrict__ zi8, int row0) {
  __shared__ float g[32][DIMX];
  const int t = threadIdx.x;
  const int lrow0 = blockIdx.x * 32;
  const int grow0 = row0 + lrow0;
  const int wv = t >> 6, lane = t & 63;
#pragma unroll
  for (int j = 0; j < 4; ++j) {
    const int r = wv * 4 + j;
    const float* xr = x + (size_t)(grow0 + r) * DIMX;
    float4 v = *(const float4*)(xr + lane * 4);
    float s = v.x + v.y + v.z + v.w;
    float ss = v.x * v.x + v.y * v.y + v.z * v.z + v.w * v.w;
#pragma unroll
    for (int o = 32; o > 0; o >>= 1) { s += __shfl_xor(s, o); ss += __shfl_xor(ss, o); }
    const float mu = s * (1.0f / 256.0f);
    const float var = ss * (1.0f / 256.0f) - mu * mu;
    const float rstd = rsqrtf(var + 1e-5f);
    float vv[4] = {v.x, v.y, v.z, v.w};
#pragma unroll
    for (int q = 0; q < 4; ++q) {
      const int d = lane * 4 + q;
      float xn = (vv[q] - mu) * rstd * ln_g[d] + ln_b[d];
      g[r][d] = 0.5f * xn * (1.0f + erff(xn * 0.70710678118654752f));
    }
  }
  __syncthreads();
  float acc[32][2];
#pragma unroll
  for (int r = 0; r < 32; ++r) { acc[r][0] = 0.f; acc[r][1] = 0.f; }
#pragma unroll 2
  for (int d0 = 0; d0 < DIMX; d0 += 4) {
    float2 w0 = *(const float2*)(w_pre + (size_t)(d0 + 0) * CDIM + t * 2);
    float2 w1 = *(const float2*)(w_pre + (size_t)(d0 + 1) * CDIM + t * 2);
    float2 w2 = *(const float2*)(w_pre + (size_t)(d0 + 2) * CDIM + t * 2);
    float2 w3 = *(const float2*)(w_pre + (size_t)(d0 + 3) * CDIM + t * 2);
#pragma unroll
    for (int r = 0; r < 32; ++r) {
      float4 gv = *(const float4*)&g[r][d0];
      acc[r][0] = fmaf(gv.x, w0.x, acc[r][0]);
      acc[r][1] = fmaf(gv.x, w0.y, acc[r][1]);
      acc[r][0] = fmaf(gv.y, w1.x, acc[r][0]);
      acc[r][1] = fmaf(gv.y, w1.y, acc[r][1]);
      acc[r][0] = fmaf(gv.z, w2.x, acc[r][0]);
      acc[r][1] = fmaf(gv.z, w2.y, acc[r][1]);
      acc[r][0] = fmaf(gv.w, w3.x, acc[r][0]);
      acc[r][1] = fmaf(gv.w, w3.y, acc[r][1]);
    }
  }
  float2 bp = *(const float2*)(b_pre + t * 2);
#pragma unroll
  for (int r = 0; r < 32; ++r) {
    float2 o;
    o.x = acc[r][0] + bp.x;
    o.y = acc[r][1] + bp.y;
    *(float2*)(zf + (size_t)(lrow0 + r) * CDIM + t * 2) = o;
    char2 c2;
    c2.x = q8(o.x);
    c2.y = q8(o.y);
    *(char2*)(zi8 + (size_t)(lrow0 + r) * CDIM + t * 2) = c2;
  }
}

// ---------------- K2: int8 MFMA coarse scorer + candidate collect ----------
// grid = (chunk/256)*NSP ; block = 512 (8 waves: 2M x 4N)
// ring-2 x 32KB LDS, BK=64 i8, 16 K-tiles  (r12-proven structure, unchanged)
__global__ __launch_bounds__(512) void k_score(
    const char* __restrict__ Ei8, const char* __restrict__ Zi8,
    const float* __restrict__ e_sq, uint2* __restrict__ cand, int chunk) {
  __shared__ __align__(16) char lds[2][32768];
  const int t = threadIdx.x;
  const int cpx = gridDim.x >> 3;  // bijective XCD swizzle, grid % 8 == 0
  const int bx = (blockIdx.x & 7) * cpx + (blockIdx.x >> 3);
  const int zblk = bx / NSP, csp = bx % NSP;
  const int wid = t >> 6, l = t & 63;
  const int wr = wid >> 2, wc = wid & 3;
  const int lg = l >> 4, lo16 = l & 15;
  const int rowbase = zblk * 256;
  const int m0 = csp * 256;
  const int wr8 = wr * 8, wc4 = wc * 4, l16 = l * 16;

  const bool isA = (wid < 4);
  const int q = wid & 3;
  const char* sarr = isA ? Ei8 : Zi8;
  const int sbase = isA ? m0 : rowbase;
  const char* sp0 = sarr + (size_t)(sbase + q * 64 + lo16) * 1024 + lg * 16;
  const int dstbase = (isA ? 0 : 16384) + q * 4096;

  i32x4 acc[8][4];
#pragma unroll
  for (int mi = 0; mi < 8; ++mi)
#pragma unroll
    for (int ni = 0; ni < 4; ++ni) acc[mi][ni] = (i32x4){0, 0, 0, 0};

  // prologue: stage tile 0 into buf 0
  {
    char* D = &lds[0][dstbase];
#pragma unroll
    for (int u = 0; u < 4; ++u) GLOAD_LDS16(sp0 + u * 16384, D + u * 1024);
  }

  for (int kt = 0; kt < 16; ++kt) {
    const char* Lc = lds[kt & 1];
    asm volatile("s_waitcnt vmcnt(0)" ::: "memory");
    __builtin_amdgcn_s_barrier();
    __builtin_amdgcn_sched_barrier(0);
    // issue next tile early (full kt of flight time)
    if (kt < 15) {
      char* Dst = &lds[(kt + 1) & 1][dstbase];
      const char* spk = sp0 + (kt + 1) * 64;
#pragma unroll
      for (int u = 0; u < 4; ++u) GLOAD_LDS16(spk + u * 16384, Dst + u * 1024);
    }
    i32x4 bh[4], a[8];
#pragma unroll
    for (int ni = 0; ni < 4; ++ni)
      bh[ni] = *(const i32x4*)(Lc + 16384 + (wc4 + ni) * 1024 + l16);
#pragma unroll
    for (int u = 0; u < 8; ++u)
      a[u] = *(const i32x4*)(Lc + (wr8 + u) * 1024 + l16);
    asm volatile("s_waitcnt lgkmcnt(0)" ::: "memory");
    __builtin_amdgcn_sched_barrier(0);
    __builtin_amdgcn_s_setprio(1);
#pragma unroll
    for (int u = 0; u < 8; ++u)
#pragma unroll
      for (int ni = 0; ni < 4; ++ni)
        acc[u][ni] = __builtin_amdgcn_mfma_i32_16x16x64_i8(a[u], bh[ni],
                                                           acc[u][ni], 0, 0, 0);
    __builtin_amdgcn_s_setprio(0);
  }

  // ---- epilogue: strip-min + candidate collect ----
  float s1[4];
  int i1[4];
#pragma unroll
  for (int i = 0; i < 4; ++i) { s1[i] = FLT_BIG; i1[i] = 0x7fffffff; }
#pragma unroll
  for (int mi = 0; mi < 8; ++mi) {
    const int c0 = m0 + wr * 128 + mi * 16 + lg * 4;
    float4 es = *(const float4*)(e_sq + c0);
    float esv[4] = {es.x, es.y, es.z, es.w};
#pragma unroll
    for (int ni = 0; ni < 4; ++ni) {
#pragma unroll
      for (int j = 0; j < 4; ++j) {
        const float s = fmaf(-2.0f * INV_S2, (float)acc[mi][ni][j], esv[j]);
        const int c = c0 + j;
        if (s < s1[ni] || (s == s1[ni] && c < i1[ni])) { s1[ni] = s; i1[ni] = c; }
      }
    }
  }

  unsigned long long* red = (unsigned long long*)&lds[0][0];  // 512 u64, 4KB
  float* sb = (float*)&lds[0][4096];                          // 256 f32
  unsigned* sbi = (unsigned*)&lds[0][5120];                   // 256 u32
  unsigned* cnt = (unsigned*)&lds[0][6144];                   // 256 u32
  uint2* slot = (uint2*)&lds[0][7168];                        // 256*NSLOT*8B

  __syncthreads();
#pragma unroll
  for (int ni = 0; ni < 4; ++ni) {
    unsigned long long k1v =
        (((unsigned long long)fkey(s1[ni])) << 32) | (unsigned)i1[ni];
    unsigned long long o1 = __shfl_xor(k1v, 16);
    k1v = o1 < k1v ? o1 : k1v;
    o1 = __shfl_xor(k1v, 32);
    k1v = o1 < k1v ? o1 : k1v;
    if (lg == 0) {
      const int r = wc * 64 + ni * 16 + lo16;
      red[r * 2 + wr] = k1v;
    }
  }
  __syncthreads();
  if (t < 256) {
    unsigned long long a1 = red[t * 2 + 0], b1 = red[t * 2 + 1];
    if (b1 < a1) a1 = b1;
    sb[t] = keyinv((unsigned)(a1 >> 32));
    sbi[t] = (unsigned)(a1 & 0xFFFFFFFFull);
    cnt[t] = 0;
  }
  __syncthreads();
#pragma unroll
  for (int mi = 0; mi < 8; ++mi) {
    const int c0 = m0 + wr * 128 + mi * 16 + lg * 4;
    float4 es = *(const float4*)(e_sq + c0);
    float esv[4] = {es.x, es.y, es.z, es.w};
#pragma unroll
    for (int ni = 0; ni < 4; ++ni) {
      const int r = wc * 64 + ni * 16 + lo16;
      const float thr = sb[r] + CMARG;
#pragma unroll
      for (int j = 0; j < 4; ++j) {
        const float s = fmaf(-2.0f * INV_S2, (float)acc[mi][ni][j], esv[j]);
        const unsigned c = (unsigned)(c0 + j);
        if (s < thr && c != sbi[r]) {
          unsigned pos = atomicAdd(&cnt[r], 1u);
          if (pos < NSLOT)
            slot[r * NSLOT + pos] = make_uint2(__float_as_uint(s), c);
        }
      }
    }
  }
  __syncthreads();
  if (t < 256) {
    // row-major: NENT entries per (row,strip), 96 per row
    uint2* g = cand + (size_t)(rowbase + t) * (NSP * NENT) + csp * NENT;
    const unsigned ov = (cnt[t] > NSLOT) ? 0x40000000u : 0u;
    g[0] = make_uint2(__float_as_uint(sb[t]), sbi[t] | ov);
    const unsigned n = cnt[t] > NSLOT ? NSLOT : cnt[t];
#pragma unroll
    for (int k = 0; k < NSLOT; ++k)
      g[1 + k] = (k < (int)n) ? slot[t * NSLOT + k]
                              : make_uint2(__float_as_uint(FLT_BIG), 0xFFFFFFFFu);
  }
}

// ---------------- K3: exact f64 refine on fp32 z over candidates ------------
// block = 512 (8 waves), 8 rows/block
__global__ __launch_bounds__(512) void k_refine(
    const uint2* __restrict__ cand, const float* __restrict__ zf,
    const float* __restrict__ embed, int* __restrict__ idxf,
    float* __restrict__ crow, float* __restrict__ out_idx,
    int* __restrict__ flag_rows, int* __restrict__ nflag, int chunk,
    int row0) {
  const int t = threadIdx.x, wid = t >> 6, l = t & 63;
  const int lrow = blockIdx.x * 8 + wid;
  if (lrow >= chunk) return;
  const int grow = row0 + lrow;
  const uint2* base = cand + (size_t)lrow * (NSP * NENT);
  const uint2 e0 = base[l];
  const uint2 e1 = (l < 32) ? base[64 + l]
                            : make_uint2(__float_as_uint(FLT_BIG), 0xFFFFFFFFu);
  const bool is0 = (l % NENT) == 0;
  const bool is1 = (l < 32) && (((64 + l) % NENT) == 0);
  float gm = FLT_BIG;
  if (is0) gm = fminf(gm, __uint_as_float(e0.x));
  if (is1) gm = fminf(gm, __uint_as_float(e1.x));
#pragma unroll
  for (int o = 32; o > 0; o >>= 1) gm = fminf(gm, __shfl_xor(gm, o));
  const float thr = gm + RMARG;
  bool myovf = (is0 && (e0.y & 0x40000000u) && __uint_as_float(e0.x) < thr) ||
               (is1 && (e1.y & 0x40000000u) && __uint_as_float(e1.x) < thr);
  const bool ovf = __any(myovf);

  float zv[16];
#pragma unroll
  for (int j = 0; j < 16; ++j) zv[j] = zf[(size_t)lrow * CDIM + l + 64 * j];

  double d1 = 1e300;
  int i1 = 0x7fffffff;
#define PROC(E)                                                                \
  {                                                                            \
    const float sc_ = __uint_as_float(E.x);                                    \
    const int id_ = (int)(E.y & 0xFFFFu);                                      \
    unsigned long long mask = __ballot(sc_ < thr && id_ < KCODES);             \
    while (mask) {                                                             \
      const int src = __ffsll((unsigned long long)mask) - 1;                   \
      mask &= mask - 1;                                                        \
      const int c = __shfl(id_, src);                                          \
      const float* e = embed + (size_t)c * CDIM;                               \
      double dd = 0.0;                                                         \
      _Pragma("unroll") for (int j = 0; j < 16; ++j) {                         \
        const double df = (double)zv[j] - (double)e[l + 64 * j];               \
        dd = fma(df, df, dd);                                                  \
      }                                                                        \
      _Pragma("unroll") for (int o = 32; o > 0; o >>= 1) dd +=                 \
          __shfl_xor(dd, o);                                                   \
      if (dd < d1 || (dd == d1 && c < i1)) { d1 = dd; i1 = c; }                \
    }                                                                          \
  }
  PROC(e0);
  PROC(e1);
#undef PROC
  if (l == 0) {
    idxf[grow] = i1;
    out_idx[grow] = (float)i1;
    crow[grow] = (float)d1;
    if (ovf) {
      const int s = atomicAdd(nflag, 1);
      flag_rows[s] = lrow;
    }
  }
}

// ---------------- K3b: exact f64 full rescan (overflow rows only) -----------
__global__ __launch_bounds__(256) void k_exact(
    const float* __restrict__ zf, const float* __restrict__ embed,
    const int* __restrict__ flag_rows, const int* __restrict__ nflag,
    int* __restrict__ idxf, float* __restrict__ crow,
    float* __restrict__ out_idx, int row0) {
  __shared__ double wd[4];
  __shared__ int wcidx[4];
  const int t = threadIdx.x;
  const int wid = t >> 6, l = t & 63;
  const int n = *nflag;

  for (int fi = blockIdx.x; fi < n; fi += gridDim.x) {
    const int lrow = flag_rows[fi];
    const int grow = row0 + lrow;
    float zr[16];
#pragma unroll
    for (int j = 0; j < 16; ++j) zr[j] = zf[(size_t)lrow * CDIM + l + 64 * j];
    double dmin = 1e300;
    int cmin = 0x7fffffff;
    for (int ci = 0; ci < 1024; ++ci) {
      const int c = wid * 1024 + ci;
      const float* e = embed + (size_t)c * CDIM;
      double dd = 0.0;
#pragma unroll
      for (int j = 0; j < 16; ++j) {
        const double df = (double)zr[j] - (double)e[l + 64 * j];
        dd = fma(df, df, dd);
      }
#pragma unroll
      for (int o = 32; o > 0; o >>= 1) dd += __shfl_xor(dd, o);
      if (dd < dmin) { dmin = dd; cmin = c; }
    }
    if (l == 0) { wd[wid] = dmin; wcidx[wid] = cmin; }
    __syncthreads();
    if (t == 0) {
      double dm = wd[0]; int cm = wcidx[0];
#pragma unroll
      for (int wv = 1; wv < 4; ++wv) {
        if (wd[wv] < dm || (wd[wv] == dm && wcidx[wv] < cm)) {
          dm = wd[wv]; cm = wcidx[wv];
        }
      }
      idxf[grow] = cm;
      out_idx[grow] = (float)cm;
      crow[grow] = (float)dm;
    }
    __syncthreads();
  }
}

// ---------------- K4: E_post = embed @ w_post ----------------
__global__ __launch_bounds__(256) void k_epost(const float* __restrict__ E,
                                               const float* __restrict__ w_post,
                                               float* __restrict__ E_post) {
  __shared__ float es[16][128];
  const int t = threadIdx.x;
  const int r0 = blockIdx.x * 16;
  float acc[16];
#pragma unroll
  for (int r = 0; r < 16; ++r) acc[r] = 0.f;
  for (int k0 = 0; k0 < CDIM; k0 += 128) {
    __syncthreads();
#pragma unroll
    for (int p = 0; p < 2; ++p) {
      const int fl = (p * 256 + t) * 4;
      const int r = fl >> 7, kk = fl & 127;
      float4 v = *(const float4*)(E + (size_t)(r0 + r) * CDIM + k0 + kk);
      *(float4*)&es[r][kk] = v;
    }
    __syncthreads();
#pragma unroll 4
    for (int d = 0; d < 128; ++d) {
      const float w = w_post[(size_t)(k0 + d) * DIMX + t];
#pragma unroll
      for (int r = 0; r < 16; ++r) acc[r] = fmaf(es[r][d], w, acc[r]);
    }
  }
#pragma unroll
  for (int r = 0; r < 16; ++r)
    E_post[(size_t)(r0 + r) * DIMX + t] = acc[r];
}

// ---------------- K5: gather E_post rows + bias ----------------
__global__ __launch_bounds__(256) void k_gather(const float* __restrict__ E_post,
                                                const int* __restrict__ idx,
                                                const float* __restrict__ b_post,
                                                float* __restrict__ outq) {
  const int t = threadIdx.x;
  const int r0 = blockIdx.x * 16;
  const float bp = b_post[t];
#pragma unroll
  for (int i = 0; i < 16; ++i) {
    const int row = r0 + i;
    outq[(size_t)row * DIMX + t] = E_post[(size_t)idx[row] * DIMX + t] + bp;
  }
}

// ---------------- K6: commit reduce ----------------
__global__ __launch_bounds__(256) void k_commit_final(
    const float* __restrict__ crow, float* __restrict__ out_commit) {
  const int t = threadIdx.x;
  double s = 0.0;
  for (int i = t; i < BN_ROWS; i += 256) s += (double)crow[i];
#pragma unroll
  for (int o = 32; o > 0; o >>= 1) s += __shfl_xor(s, o);
  __shared__ double wsum[4];
  if ((t & 63) == 0) wsum[t >> 6] = s;
  __syncthreads();
  if (t == 0)
    *out_commit = (float)(0.25 * (wsum[0] + wsum[1] + wsum[2] + wsum[3]) /
                          (65536.0 * 1024.0));
}

extern "C" void kernel_launch(void* const* d_in, const int* in_sizes, int n_in,
                              void* d_out, int out_size, void* d_ws,
                              size_t ws_size, hipStream_t stream) {
  const float* x = (const float*)d_in[0];
  const float* ln_g = (const float*)d_in[1];
  const float* ln_b = (const float*)d_in[2];
  const float* w_pre = (const float*)d_in[3];
  const float* b_pre = (const float*)d_in[4];
  const float* embed = (const float*)d_in[5];
  const float* w_post = (const float*)d_in[6];
  const float* b_post = (const float*)d_in[7];

  float* out = (float*)d_out;
  float* outq = out;                   // 16777216 f32
  float* out_idx = out + 16777216;     // 65536 f32
  float* out_commit = out + 16842752;  // 1 f32

  char* ws = (char*)d_ws;
  float* e_sq = (float*)(ws + OFF_ESQ);
  int* idxf = (int*)(ws + OFF_IDXF);
  float* crow = (float*)(ws + OFF_CROW);
  float* E_post = (float*)(ws + OFF_EPOST);
  char* Ei8 = (char*)(ws + OFF_EI8);
  int* nflag = (int*)(ws + OFF_NFLAG);
  int* flag_rows = (int*)(ws + OFF_FLAG);

  // largest power-of-2 chunk (>=4096) with OFF_CAND + chunk*5888 <= ws_size
  int chunk = 4096;
  while (chunk < BN_ROWS &&
         OFF_CAND + (size_t)(chunk * 2) * 5888ull <= ws_size)
    chunk *= 2;
  uint2* cand = (uint2*)(ws + OFF_CAND);
  char* zi8 = ws + OFF_CAND + (size_t)chunk * 768;
  float* zf = (float*)(ws + OFF_CAND + (size_t)chunk * 768 +
                       (size_t)chunk * 1024);

  k_prep_e<<<KCODES, 256, 0, stream>>>(embed, e_sq, Ei8);
  k_epost<<<KCODES / 16, 256, 0, stream>>>(embed, w_post, E_post);

  for (int row0 = 0; row0 < BN_ROWS; row0 += chunk) {
    hipMemsetAsync(nflag, 0, sizeof(int), stream);
    k_ln_gelu_gemm<<<chunk / 32, 512, 0, stream>>>(x, ln_g, ln_b, w_pre, b_pre,
                                                   zf, zi8, row0);
    k_score<<<(chunk / 256) * NSP, 512, 0, stream>>>(Ei8, zi8, e_sq, cand,
                                                     chunk);
    k_refine<<<chunk / 8, 512, 0, stream>>>(cand, zf, embed, idxf, crow,
                                            out_idx, flag_rows, nflag, chunk,
                                            row0);
    k_exact<<<128, 256, 0, stream>>>(zf, embed, flag_rows, nflag, idxf, crow,
                                     out_idx, row0);
  }

  k_gather<<<BN_ROWS / 16, 256, 0, stream>>>(E_post, idxf, b_post, outq);
  k_commit_final<<<1, 256, 0, stream>>>(crow, out_commit);
}

// Round 19
// 1330.688 us; speedup vs baseline: 1.0563x; 1.0563x over previous
//
#include <hip/hip_runtime.h>

#define BN_ROWS 65536
#define DIMX 256
#define CDIM 1024
#define KCODES 4096
#define NSP 16            // code strips of 256
#define NSLOT 5           // candidate slots per strip (excl. min)
#define NENT 6            // entries per (row,strip) = 1 min + NSLOT
#define CMARG 12.0f       // strip capture margin (~10 sigma of int8 score err)
#define RMARG 12.0f       // refine filter margin above global coarse min
#define QS 24.0f          // int8 quantization scale
#define INV_S2 (1.0f / (QS * QS))
#define FLT_BIG 3.402823466e+38f

// ---------------- ws layout (bytes) ----------------
static const size_t OFF_ESQ   = 0;         // 4096 f32 (16KB)
static const size_t OFF_IDXF  = 16384;     // 65536 i32
static const size_t OFF_CROW  = 278528;    // 65536 f32
static const size_t OFF_EPOST = 540672;    // 4096*256 f32 (4MB)
static const size_t OFF_EI8   = 4734976;   // 4096*1024 i8 (4MB)
static const size_t OFF_NFLAG = 8929280;   // 1 i32 (+pad)
static const size_t OFF_FLAG  = 8929344;   // 65536 i32
static const size_t OFF_CAND  = 9191488;   // chunk * 96 entries * 8B
// zi8 = OFF_CAND + chunk*768 ; zf = zi8 + chunk*1024 (fp32 z, 4KB/row)
// per-row total: 768 + 1024 + 4096 = 5888 B

typedef __attribute__((ext_vector_type(4))) int i32x4;

#define GLOAD_LDS16(gsrc, ldst)                                                \
  __builtin_amdgcn_global_load_lds(                                            \
      (const __attribute__((address_space(1))) void*)(gsrc),                   \
      (__attribute__((address_space(3))) void*)(ldst), 16, 0, 0)

__device__ inline char q8(float f) {
  return (char)__float2int_rn(fminf(fmaxf(f * QS, -127.f), 127.f));
}
__device__ inline unsigned fkey(float s) {
  unsigned b = __float_as_uint(s);
  return b ^ ((unsigned)((int)b >> 31) | 0x80000000u);
}
__device__ inline float keyinv(unsigned k) {
  unsigned b = (k & 0x80000000u) ? (k ^ 0x80000000u) : ~k;
  return __uint_as_float(b);
}

// ---------------- K0: fused e_sq + E->int8 (single pass over embed) --------
__global__ __launch_bounds__(256) void k_prep_e(const float* __restrict__ embed,
                                                float* __restrict__ e_sq,
                                                char* __restrict__ Ei8) {
  const int t = threadIdx.x, wv = t >> 6, lane = t & 63;
  const size_t row = blockIdx.x;
  float4 v = *(const float4*)(embed + row * CDIM + t * 4);
  *(char4*)(Ei8 + row * CDIM + t * 4) =
      make_char4(q8(v.x), q8(v.y), q8(v.z), q8(v.w));
  float s = v.x * v.x + v.y * v.y + v.z * v.z + v.w * v.w;
#pragma unroll
  for (int o = 32; o > 0; o >>= 1) s += __shfl_xor(s, o);
  __shared__ float wsum[4];
  if (lane == 0) wsum[wv] = s;
  __syncthreads();
  if (t == 0) e_sq[row] = wsum[0] + wsum[1] + wsum[2] + wsum[3];
}

// ---------------- K1: LN + GELU + @w_pre -> z fp32 + z int8 (16 rows) -------
__global__ __launch_bounds__(256) void k_ln_gelu_gemm(
    const float* __restrict__ x, const float* __restrict__ ln_g,
    const float* __restrict__ ln_b, const float* __restrict__ w_pre,
    const float* __restrict__ b_pre, float* __restrict__ zf,
    char* __restrict__ zi8, int row0) {
  __shared__ float g[16][DIMX];
  const int t = threadIdx.x;
  const int lrow0 = blockIdx.x * 16;
  const int grow0 = row0 + lrow0;
  const int wv = t >> 6, lane = t & 63;
#pragma unroll
  for (int j = 0; j < 4; ++j) {
    const int r = wv * 4 + j;
    const float* xr = x + (size_t)(grow0 + r) * DIMX;
    float4 v = *(const float4*)(xr + lane * 4);
    float s = v.x + v.y + v.z + v.w;
    float ss = v.x * v.x + v.y * v.y + v.z * v.z + v.w * v.w;
#pragma unroll
    for (int o = 32; o > 0; o >>= 1) { s += __shfl_xor(s, o); ss += __shfl_xor(ss, o); }
    const float mu = s * (1.0f / 256.0f);
    const float var = ss * (1.0f / 256.0f) - mu * mu;
    const float rstd = rsqrtf(var + 1e-5f);
    float vv[4] = {v.x, v.y, v.z, v.w};
#pragma unroll
    for (int q = 0; q < 4; ++q) {
      const int d = lane * 4 + q;
      float xn = (vv[q] - mu) * rstd * ln_g[d] + ln_b[d];
      g[r][d] = 0.5f * xn * (1.0f + erff(xn * 0.70710678118654752f));
    }
  }
  __syncthreads();
  float acc[16][4];
#pragma unroll
  for (int r = 0; r < 16; ++r)
#pragma unroll
    for (int c = 0; c < 4; ++c) acc[r][c] = 0.f;
#pragma unroll 2
  for (int d0 = 0; d0 < DIMX; d0 += 4) {
    float4 w0 = *(const float4*)(w_pre + (size_t)(d0 + 0) * CDIM + t * 4);
    float4 w1 = *(const float4*)(w_pre + (size_t)(d0 + 1) * CDIM + t * 4);
    float4 w2 = *(const float4*)(w_pre + (size_t)(d0 + 2) * CDIM + t * 4);
    float4 w3 = *(const float4*)(w_pre + (size_t)(d0 + 3) * CDIM + t * 4);
#pragma unroll
    for (int r = 0; r < 16; ++r) {
      float4 gv = *(const float4*)&g[r][d0];
      acc[r][0] = fmaf(gv.x, w0.x, acc[r][0]);
      acc[r][1] = fmaf(gv.x, w0.y, acc[r][1]);
      acc[r][2] = fmaf(gv.x, w0.z, acc[r][2]);
      acc[r][3] = fmaf(gv.x, w0.w, acc[r][3]);
      acc[r][0] = fmaf(gv.y, w1.x, acc[r][0]);
      acc[r][1] = fmaf(gv.y, w1.y, acc[r][1]);
      acc[r][2] = fmaf(gv.y, w1.z, acc[r][2]);
      acc[r][3] = fmaf(gv.y, w1.w, acc[r][3]);
      acc[r][0] = fmaf(gv.z, w2.x, acc[r][0]);
      acc[r][1] = fmaf(gv.z, w2.y, acc[r][1]);
      acc[r][2] = fmaf(gv.z, w2.z, acc[r][2]);
      acc[r][3] = fmaf(gv.z, w2.w, acc[r][3]);
      acc[r][0] = fmaf(gv.w, w3.x, acc[r][0]);
      acc[r][1] = fmaf(gv.w, w3.y, acc[r][1]);
      acc[r][2] = fmaf(gv.w, w3.z, acc[r][2]);
      acc[r][3] = fmaf(gv.w, w3.w, acc[r][3]);
    }
  }
  float4 bp = *(const float4*)(b_pre + t * 4);
#pragma unroll
  for (int r = 0; r < 16; ++r) {
    float4 o;
    o.x = acc[r][0] + bp.x; o.y = acc[r][1] + bp.y;
    o.z = acc[r][2] + bp.z; o.w = acc[r][3] + bp.w;
    *(float4*)(zf + (size_t)(lrow0 + r) * CDIM + t * 4) = o;
    *(char4*)(zi8 + (size_t)(lrow0 + r) * CDIM + t * 4) =
        make_char4(q8(o.x), q8(o.y), q8(o.z), q8(o.w));
  }
}

// ---------------- K2: int8 MFMA coarse scorer + candidate collect ----------
// grid = (chunk/256)*NSP ; block = 512 (8 waves: 2M x 4N)
// ring-2 x 32KB LDS, BK=64 i8, 16 K-tiles  (r12-proven structure, unchanged)
__global__ __launch_bounds__(512) void k_score(
    const char* __restrict__ Ei8, const char* __restrict__ Zi8,
    const float* __restrict__ e_sq, uint2* __restrict__ cand, int chunk) {
  __shared__ __align__(16) char lds[2][32768];
  const int t = threadIdx.x;
  const int cpx = gridDim.x >> 3;  // bijective XCD swizzle, grid % 8 == 0
  const int bx = (blockIdx.x & 7) * cpx + (blockIdx.x >> 3);
  const int zblk = bx / NSP, csp = bx % NSP;
  const int wid = t >> 6, l = t & 63;
  const int wr = wid >> 2, wc = wid & 3;
  const int lg = l >> 4, lo16 = l & 15;
  const int rowbase = zblk * 256;
  const int m0 = csp * 256;
  const int wr8 = wr * 8, wc4 = wc * 4, l16 = l * 16;

  const bool isA = (wid < 4);
  const int q = wid & 3;
  const char* sarr = isA ? Ei8 : Zi8;
  const int sbase = isA ? m0 : rowbase;
  const char* sp0 = sarr + (size_t)(sbase + q * 64 + lo16) * 1024 + lg * 16;
  const int dstbase = (isA ? 0 : 16384) + q * 4096;

  i32x4 acc[8][4];
#pragma unroll
  for (int mi = 0; mi < 8; ++mi)
#pragma unroll
    for (int ni = 0; ni < 4; ++ni) acc[mi][ni] = (i32x4){0, 0, 0, 0};

  // prologue: stage tile 0 into buf 0
  {
    char* D = &lds[0][dstbase];
#pragma unroll
    for (int u = 0; u < 4; ++u) GLOAD_LDS16(sp0 + u * 16384, D + u * 1024);
  }

  for (int kt = 0; kt < 16; ++kt) {
    const char* Lc = lds[kt & 1];
    asm volatile("s_waitcnt vmcnt(0)" ::: "memory");
    __builtin_amdgcn_s_barrier();
    __builtin_amdgcn_sched_barrier(0);
    // issue next tile early (full kt of flight time)
    if (kt < 15) {
      char* Dst = &lds[(kt + 1) & 1][dstbase];
      const char* spk = sp0 + (kt + 1) * 64;
#pragma unroll
      for (int u = 0; u < 4; ++u) GLOAD_LDS16(spk + u * 16384, Dst + u * 1024);
    }
    i32x4 bh[4], a[8];
#pragma unroll
    for (int ni = 0; ni < 4; ++ni)
      bh[ni] = *(const i32x4*)(Lc + 16384 + (wc4 + ni) * 1024 + l16);
#pragma unroll
    for (int u = 0; u < 8; ++u)
      a[u] = *(const i32x4*)(Lc + (wr8 + u) * 1024 + l16);
    asm volatile("s_waitcnt lgkmcnt(0)" ::: "memory");
    __builtin_amdgcn_sched_barrier(0);
    __builtin_amdgcn_s_setprio(1);
#pragma unroll
    for (int u = 0; u < 8; ++u)
#pragma unroll
      for (int ni = 0; ni < 4; ++ni)
        acc[u][ni] = __builtin_amdgcn_mfma_i32_16x16x64_i8(a[u], bh[ni],
                                                           acc[u][ni], 0, 0, 0);
    __builtin_amdgcn_s_setprio(0);
  }

  // ---- epilogue: strip-min + candidate collect ----
  float s1[4];
  int i1[4];
#pragma unroll
  for (int i = 0; i < 4; ++i) { s1[i] = FLT_BIG; i1[i] = 0x7fffffff; }
#pragma unroll
  for (int mi = 0; mi < 8; ++mi) {
    const int c0 = m0 + wr * 128 + mi * 16 + lg * 4;
    float4 es = *(const float4*)(e_sq + c0);
    float esv[4] = {es.x, es.y, es.z, es.w};
#pragma unroll
    for (int ni = 0; ni < 4; ++ni) {
#pragma unroll
      for (int j = 0; j < 4; ++j) {
        const float s = fmaf(-2.0f * INV_S2, (float)acc[mi][ni][j], esv[j]);
        const int c = c0 + j;
        if (s < s1[ni] || (s == s1[ni] && c < i1[ni])) { s1[ni] = s; i1[ni] = c; }
      }
    }
  }

  unsigned long long* red = (unsigned long long*)&lds[0][0];  // 512 u64, 4KB
  float* sb = (float*)&lds[0][4096];                          // 256 f32
  unsigned* sbi = (unsigned*)&lds[0][5120];                   // 256 u32
  unsigned* cnt = (unsigned*)&lds[0][6144];                   // 256 u32
  uint2* slot = (uint2*)&lds[0][7168];                        // 256*NSLOT*8B

  __syncthreads();
#pragma unroll
  for (int ni = 0; ni < 4; ++ni) {
    unsigned long long k1v =
        (((unsigned long long)fkey(s1[ni])) << 32) | (unsigned)i1[ni];
    unsigned long long o1 = __shfl_xor(k1v, 16);
    k1v = o1 < k1v ? o1 : k1v;
    o1 = __shfl_xor(k1v, 32);
    k1v = o1 < k1v ? o1 : k1v;
    if (lg == 0) {
      const int r = wc * 64 + ni * 16 + lo16;
      red[r * 2 + wr] = k1v;
    }
  }
  __syncthreads();
  if (t < 256) {
    unsigned long long a1 = red[t * 2 + 0], b1 = red[t * 2 + 1];
    if (b1 < a1) a1 = b1;
    sb[t] = keyinv((unsigned)(a1 >> 32));
    sbi[t] = (unsigned)(a1 & 0xFFFFFFFFull);
    cnt[t] = 0;
  }
  __syncthreads();
#pragma unroll
  for (int mi = 0; mi < 8; ++mi) {
    const int c0 = m0 + wr * 128 + mi * 16 + lg * 4;
    float4 es = *(const float4*)(e_sq + c0);
    float esv[4] = {es.x, es.y, es.z, es.w};
#pragma unroll
    for (int ni = 0; ni < 4; ++ni) {
      const int r = wc * 64 + ni * 16 + lo16;
      const float thr = sb[r] + CMARG;
#pragma unroll
      for (int j = 0; j < 4; ++j) {
        const float s = fmaf(-2.0f * INV_S2, (float)acc[mi][ni][j], esv[j]);
        const unsigned c = (unsigned)(c0 + j);
        if (s < thr && c != sbi[r]) {
          unsigned pos = atomicAdd(&cnt[r], 1u);
          if (pos < NSLOT)
            slot[r * NSLOT + pos] = make_uint2(__float_as_uint(s), c);
        }
      }
    }
  }
  __syncthreads();
  if (t < 256) {
    // row-major: NENT entries per (row,strip), 96 per row
    uint2* g = cand + (size_t)(rowbase + t) * (NSP * NENT) + csp * NENT;
    const unsigned ov = (cnt[t] > NSLOT) ? 0x40000000u : 0u;
    g[0] = make_uint2(__float_as_uint(sb[t]), sbi[t] | ov);
    const unsigned n = cnt[t] > NSLOT ? NSLOT : cnt[t];
#pragma unroll
    for (int k = 0; k < NSLOT; ++k)
      g[1 + k] = (k < (int)n) ? slot[t * NSLOT + k]
                              : make_uint2(__float_as_uint(FLT_BIG), 0xFFFFFFFFu);
  }
}

// ---------------- K3: exact f64 refine on fp32 z over candidates ------------
// block = 512 (8 waves), 8 rows/block
__global__ __launch_bounds__(512) void k_refine(
    const uint2* __restrict__ cand, const float* __restrict__ zf,
    const float* __restrict__ embed, int* __restrict__ idxf,
    float* __restrict__ crow, float* __restrict__ out_idx,
    int* __restrict__ flag_rows, int* __restrict__ nflag, int chunk,
    int row0) {
  const int t = threadIdx.x, wid = t >> 6, l = t & 63;
  const int lrow = blockIdx.x * 8 + wid;
  if (lrow >= chunk) return;
  const int grow = row0 + lrow;
  const uint2* base = cand + (size_t)lrow * (NSP * NENT);
  const uint2 e0 = base[l];
  const uint2 e1 = (l < 32) ? base[64 + l]
                            : make_uint2(__float_as_uint(FLT_BIG), 0xFFFFFFFFu);
  const bool is0 = (l % NENT) == 0;
  const bool is1 = (l < 32) && (((64 + l) % NENT) == 0);
  float gm = FLT_BIG;
  if (is0) gm = fminf(gm, __uint_as_float(e0.x));
  if (is1) gm = fminf(gm, __uint_as_float(e1.x));
#pragma unroll
  for (int o = 32; o > 0; o >>= 1) gm = fminf(gm, __shfl_xor(gm, o));
  const float thr = gm + RMARG;
  bool myovf = (is0 && (e0.y & 0x40000000u) && __uint_as_float(e0.x) < thr) ||
               (is1 && (e1.y & 0x40000000u) && __uint_as_float(e1.x) < thr);
  const bool ovf = __any(myovf);

  float zv[16];
#pragma unroll
  for (int j = 0; j < 16; ++j) zv[j] = zf[(size_t)lrow * CDIM + l + 64 * j];

  double d1 = 1e300;
  int i1 = 0x7fffffff;
#define PROC(E)                                                                \
  {                                                                            \
    const float sc_ = __uint_as_float(E.x);                                    \
    const int id_ = (int)(E.y & 0xFFFFu);                                      \
    unsigned long long mask = __ballot(sc_ < thr && id_ < KCODES);             \
    while (mask) {                                                             \
      const int src = __ffsll((unsigned long long)mask) - 1;                   \
      mask &= mask - 1;                                                        \
      const int c = __shfl(id_, src);                                          \
      const float* e = embed + (size_t)c * CDIM;                               \
      double dd = 0.0;                                                         \
      _Pragma("unroll") for (int j = 0; j < 16; ++j) {                         \
        const double df = (double)zv[j] - (double)e[l + 64 * j];               \
        dd = fma(df, df, dd);                                                  \
      }                                                                        \
      _Pragma("unroll") for (int o = 32; o > 0; o >>= 1) dd +=                 \
          __shfl_xor(dd, o);                                                   \
      if (dd < d1 || (dd == d1 && c < i1)) { d1 = dd; i1 = c; }                \
    }                                                                          \
  }
  PROC(e0);
  PROC(e1);
#undef PROC
  if (l == 0) {
    idxf[grow] = i1;
    out_idx[grow] = (float)i1;
    crow[grow] = (float)d1;
    if (ovf) {
      const int s = atomicAdd(nflag, 1);
      flag_rows[s] = lrow;
    }
  }
}

// ---------------- K3b: exact f64 full rescan (overflow rows only) -----------
__global__ __launch_bounds__(256) void k_exact(
    const float* __restrict__ zf, const float* __restrict__ embed,
    const int* __restrict__ flag_rows, const int* __restrict__ nflag,
    int* __restrict__ idxf, float* __restrict__ crow,
    float* __restrict__ out_idx, int row0) {
  __shared__ double wd[4];
  __shared__ int wcidx[4];
  const int t = threadIdx.x;
  const int wid = t >> 6, l = t & 63;
  const int n = *nflag;

  for (int fi = blockIdx.x; fi < n; fi += gridDim.x) {
    const int lrow = flag_rows[fi];
    const int grow = row0 + lrow;
    float zr[16];
#pragma unroll
    for (int j = 0; j < 16; ++j) zr[j] = zf[(size_t)lrow * CDIM + l + 64 * j];
    double dmin = 1e300;
    int cmin = 0x7fffffff;
    for (int ci = 0; ci < 1024; ++ci) {
      const int c = wid * 1024 + ci;
      const float* e = embed + (size_t)c * CDIM;
      double dd = 0.0;
#pragma unroll
      for (int j = 0; j < 16; ++j) {
        const double df = (double)zr[j] - (double)e[l + 64 * j];
        dd = fma(df, df, dd);
      }
#pragma unroll
      for (int o = 32; o > 0; o >>= 1) dd += __shfl_xor(dd, o);
      if (dd < dmin) { dmin = dd; cmin = c; }
    }
    if (l == 0) { wd[wid] = dmin; wcidx[wid] = cmin; }
    __syncthreads();
    if (t == 0) {
      double dm = wd[0]; int cm = wcidx[0];
#pragma unroll
      for (int wv = 1; wv < 4; ++wv) {
        if (wd[wv] < dm || (wd[wv] == dm && wcidx[wv] < cm)) {
          dm = wd[wv]; cm = wcidx[wv];
        }
      }
      idxf[grow] = cm;
      out_idx[grow] = (float)cm;
      crow[grow] = (float)dm;
    }
    __syncthreads();
  }
}

// ---------------- K4: E_post = embed @ w_post ----------------
__global__ __launch_bounds__(256) void k_epost(const float* __restrict__ E,
                                               const float* __restrict__ w_post,
                                               float* __restrict__ E_post) {
  __shared__ float es[16][128];
  const int t = threadIdx.x;
  const int r0 = blockIdx.x * 16;
  float acc[16];
#pragma unroll
  for (int r = 0; r < 16; ++r) acc[r] = 0.f;
  for (int k0 = 0; k0 < CDIM; k0 += 128) {
    __syncthreads();
#pragma unroll
    for (int p = 0; p < 2; ++p) {
      const int fl = (p * 256 + t) * 4;
      const int r = fl >> 7, kk = fl & 127;
      float4 v = *(const float4*)(E + (size_t)(r0 + r) * CDIM + k0 + kk);
      *(float4*)&es[r][kk] = v;
    }
    __syncthreads();
#pragma unroll 4
    for (int d = 0; d < 128; ++d) {
      const float w = w_post[(size_t)(k0 + d) * DIMX + t];
#pragma unroll
      for (int r = 0; r < 16; ++r) acc[r] = fmaf(es[r][d], w, acc[r]);
    }
  }
#pragma unroll
  for (int r = 0; r < 16; ++r)
    E_post[(size_t)(r0 + r) * DIMX + t] = acc[r];
}

// ---------------- K5: gather E_post rows + bias ----------------
__global__ __launch_bounds__(256) void k_gather(const float* __restrict__ E_post,
                                                const int* __restrict__ idx,
                                                const float* __restrict__ b_post,
                                                float* __restrict__ outq) {
  const int t = threadIdx.x;
  const int r0 = blockIdx.x * 16;
  const float bp = b_post[t];
#pragma unroll
  for (int i = 0; i < 16; ++i) {
    const int row = r0 + i;
    outq[(size_t)row * DIMX + t] = E_post[(size_t)idx[row] * DIMX + t] + bp;
  }
}

// ---------------- K6: commit reduce ----------------
__global__ __launch_bounds__(256) void k_commit_final(
    const float* __restrict__ crow, float* __restrict__ out_commit) {
  const int t = threadIdx.x;
  double s = 0.0;
  for (int i = t; i < BN_ROWS; i += 256) s += (double)crow[i];
#pragma unroll
  for (int o = 32; o > 0; o >>= 1) s += __shfl_xor(s, o);
  __shared__ double wsum[4];
  if ((t & 63) == 0) wsum[t >> 6] = s;
  __syncthreads();
  if (t == 0)
    *out_commit = (float)(0.25 * (wsum[0] + wsum[1] + wsum[2] + wsum[3]) /
                          (65536.0 * 1024.0));
}

extern "C" void kernel_launch(void* const* d_in, const int* in_sizes, int n_in,
                              void* d_out, int out_size, void* d_ws,
                              size_t ws_size, hipStream_t stream) {
  const float* x = (const float*)d_in[0];
  const float* ln_g = (const float*)d_in[1];
  const float* ln_b = (const float*)d_in[2];
  const float* w_pre = (const float*)d_in[3];
  const float* b_pre = (const float*)d_in[4];
  const float* embed = (const float*)d_in[5];
  const float* w_post = (const float*)d_in[6];
  const float* b_post = (const float*)d_in[7];

  float* out = (float*)d_out;
  float* outq = out;                   // 16777216 f32
  float* out_idx = out + 16777216;     // 65536 f32
  float* out_commit = out + 16842752;  // 1 f32

  char* ws = (char*)d_ws;
  float* e_sq = (float*)(ws + OFF_ESQ);
  int* idxf = (int*)(ws + OFF_IDXF);
  float* crow = (float*)(ws + OFF_CROW);
  float* E_post = (float*)(ws + OFF_EPOST);
  char* Ei8 = (char*)(ws + OFF_EI8);
  int* nflag = (int*)(ws + OFF_NFLAG);
  int* flag_rows = (int*)(ws + OFF_FLAG);

  // largest power-of-2 chunk (>=4096) with OFF_CAND + chunk*5888 <= ws_size
  int chunk = 4096;
  while (chunk < BN_ROWS &&
         OFF_CAND + (size_t)(chunk * 2) * 5888ull <= ws_size)
    chunk *= 2;
  uint2* cand = (uint2*)(ws + OFF_CAND);
  char* zi8 = ws + OFF_CAND + (size_t)chunk * 768;
  float* zf = (float*)(ws + OFF_CAND + (size_t)chunk * 768 +
                       (size_t)chunk * 1024);

  k_prep_e<<<KCODES, 256, 0, stream>>>(embed, e_sq, Ei8);
  k_epost<<<KCODES / 16, 256, 0, stream>>>(embed, w_post, E_post);

  for (int row0 = 0; row0 < BN_ROWS; row0 += chunk) {
    hipMemsetAsync(nflag, 0, sizeof(int), stream);
    k_ln_gelu_gemm<<<chunk / 16, 256, 0, stream>>>(x, ln_g, ln_b, w_pre, b_pre,
                                                   zf, zi8, row0);
    k_score<<<(chunk / 256) * NSP, 512, 0, stream>>>(Ei8, zi8, e_sq, cand,
                                                     chunk);
    k_refine<<<chunk / 8, 512, 0, stream>>>(cand, zf, embed, idxf, crow,
                                            out_idx, flag_rows, nflag, chunk,
                                            row0);
    k_exact<<<128, 256, 0, stream>>>(zf, embed, flag_rows, nflag, idxf, crow,
                                     out_idx, row0);
  }

  k_gather<<<BN_ROWS / 16, 256, 0, stream>>>(E_post, idxf, b_post, outq);
  k_commit_final<<<1, 256, 0, stream>>>(crow, out_commit);
}